// Round 1
// baseline (4493.254 us; speedup 1.0000x reference)
//
#include <hip/hip_runtime.h>
#include <math.h>

#define L_DEC 2306
#define T_FINE 2304

typedef float f32x4 __attribute__((ext_vector_type(4)));
typedef __bf16 bf16x8 __attribute__((ext_vector_type(8)));
typedef unsigned short us4 __attribute__((ext_vector_type(4)));
typedef unsigned short us8 __attribute__((ext_vector_type(8)));

__device__ __forceinline__ unsigned short f2bf(float f) {
  unsigned u = __float_as_uint(f);
  u += 0x7fffu + ((u >> 16) & 1u);   // RNE
  return (unsigned short)(u >> 16);
}

__device__ __forceinline__ int fix_csp(const int* p) {
  int c = p[0];
  if ((unsigned)c <= 4u) return c;
  float f = __uint_as_float((unsigned)c);   // in case harness passed a float
  int c2 = (int)f;
  return ((unsigned)c2 <= 4u) ? c2 : 4;
}

// ---------------- MFMA GEMM: C[M,N] = A[M,K] @ B ----------------
// BT=0: B is [K,N] row-major.  BT=1: B is [N,K] row-major (C = A @ B^T).
// EPI=0: store (with blockIdx.z partial offset for split-K). EPI=1: C += acc.
template<int EPI, int BT>
__global__ __launch_bounds__(256) void k_gemm(const float* __restrict__ A,
                                              const float* __restrict__ B,
                                              float* __restrict__ C,
                                              int M, int N, int K, int kchunk)
{
  __shared__ unsigned short As[128][40];   // bf16 bits, +8 pad keeps 16B rows
  __shared__ unsigned short Bs[128][40];   // stores B^T tile: Bs[n][k]
  const int tid = threadIdx.x;
  const int bm = blockIdx.y * 128;
  const int bn = blockIdx.x * 128;
  const int k0 = blockIdx.z * kchunk;
  const int w = tid >> 6, lane = tid & 63;
  const int wm = (w >> 1) * 64, wn = (w & 1) * 64;
  const int lr = lane & 15, kh = lane >> 4;

  f32x4 zero = {0.f, 0.f, 0.f, 0.f};
  f32x4 acc[4][4];
#pragma unroll
  for (int m = 0; m < 4; ++m)
#pragma unroll
    for (int n = 0; n < 4; ++n) acc[m][n] = zero;

  for (int kk = k0; kk < k0 + kchunk; kk += 32) {
    // stage A tile (128 x 32)
#pragma unroll
    for (int i = 0; i < 4; ++i) {
      int id = tid + i * 256;
      int row = id >> 3, q = (id & 7) * 4;
      int gr = bm + row;
      float4 v = make_float4(0.f, 0.f, 0.f, 0.f);
      if (gr < M) v = *(const float4*)(A + (size_t)gr * K + kk + q);
      us4 pk; pk[0] = f2bf(v.x); pk[1] = f2bf(v.y); pk[2] = f2bf(v.z); pk[3] = f2bf(v.w);
      *(us4*)&As[row][q] = pk;
    }
    // stage B tile as Bs[n][k]
    if (BT) {
#pragma unroll
      for (int i = 0; i < 4; ++i) {
        int id = tid + i * 256;
        int row = id >> 3, q = (id & 7) * 4;
        int gr = bn + row;
        float4 v = make_float4(0.f, 0.f, 0.f, 0.f);
        if (gr < N) v = *(const float4*)(B + (size_t)gr * K + kk + q);
        us4 pk; pk[0] = f2bf(v.x); pk[1] = f2bf(v.y); pk[2] = f2bf(v.z); pk[3] = f2bf(v.w);
        *(us4*)&Bs[row][q] = pk;
      }
    } else {
#pragma unroll
      for (int i = 0; i < 4; ++i) {
        int id = tid + i * 256;
        int kr = id >> 5, nc = (id & 31) * 4;
        float4 v = *(const float4*)(B + (size_t)(kk + kr) * N + bn + nc);
        Bs[nc + 0][kr] = f2bf(v.x);
        Bs[nc + 1][kr] = f2bf(v.y);
        Bs[nc + 2][kr] = f2bf(v.z);
        Bs[nc + 3][kr] = f2bf(v.w);
      }
    }
    __syncthreads();
    bf16x8 af[4], bfr[4];
#pragma unroll
    for (int m = 0; m < 4; ++m)
      af[m] = __builtin_bit_cast(bf16x8, *(const us8*)&As[wm + m * 16 + lr][kh * 8]);
#pragma unroll
    for (int n = 0; n < 4; ++n)
      bfr[n] = __builtin_bit_cast(bf16x8, *(const us8*)&Bs[wn + n * 16 + lr][kh * 8]);
#pragma unroll
    for (int m = 0; m < 4; ++m)
#pragma unroll
      for (int n = 0; n < 4; ++n)
        acc[m][n] = __builtin_amdgcn_mfma_f32_16x16x32_bf16(af[m], bfr[n], acc[m][n], 0, 0, 0);
    __syncthreads();
  }

  float* Cz = C + (size_t)blockIdx.z * M * N;  // split-K partial planes (EPI==0)
#pragma unroll
  for (int m = 0; m < 4; ++m) {
#pragma unroll
    for (int n = 0; n < 4; ++n) {
      int gc = bn + wn + n * 16 + lr;
#pragma unroll
      for (int r = 0; r < 4; ++r) {
        int gr = bm + wm + m * 16 + kh * 4 + r;
        if (gr < M) {
          size_t off = (size_t)gr * N + gc;
          if (EPI == 0) Cz[off] = acc[m][n][r];
          else          C[off] += acc[m][n][r];
        }
      }
    }
  }
}

__global__ void k_reduce16(const float* __restrict__ p, float* __restrict__ o) {
  int i = blockIdx.x * 256 + threadIdx.x;
  if (i >= 128 * 1024) return;
  float s = 0.f;
#pragma unroll
  for (int z = 0; z < 16; ++z) s += p[z * 131072 + i];
  o[i] = s;
}

// ---------------- rope table: cos/sin[18][64]; fine & decoder tables are identical ----------------
__global__ void k_rope_table(float* __restrict__ cosT, float* __restrict__ sinT) {
  int i = blockIdx.x * blockDim.x + threadIdx.x;
  if (i >= 18 * 64) return;
  int p = i >> 6, d = i & 63;
  float theta = powf(10000.f, -(float)(d & 31) / 32.f);
  float ang = (float)p * theta;
  cosT[i] = cosf(ang);
  sinT[i] = sinf(ang);
}

// ---------------- fine embed: xF[128*18][1024] ----------------
__global__ void k_fine_embed(const int* __restrict__ ids, const int* __restrict__ cspp,
                             const float* __restrict__ f_wte, const float* __restrict__ f_pos,
                             const float* __restrict__ f_adapt, float* __restrict__ xF) {
  int csp = fix_csp(cspp);
  for (int idx = blockIdx.x * 256 + threadIdx.x; idx < T_FINE * 1024; idx += gridDim.x * 256) {
    int r = idx >> 10, d = idx & 1023;
    int c = r / 18, j = r - c * 18;
    float v;
    if (j == 0)      v = f_adapt[csp * 1024 + d];
    else if (j == 1) v = f_pos[c * 1024 + d];
    else             v = f_wte[(size_t)ids[c * 16 + j - 2] * 1024 + d];
    xF[idx] = v;
  }
}

// ---------------- rmsnorm (1024 dims, one block per row) ----------------
__global__ __launch_bounds__(256) void k_rmsnorm(const float* __restrict__ x,
                                                 const float* __restrict__ w,
                                                 float* __restrict__ y) {
  int t = blockIdx.x;
  const float4 v = *(const float4*)(x + (size_t)t * 1024 + threadIdx.x * 4);
  float ss = v.x * v.x + v.y * v.y + v.z * v.z + v.w * v.w;
#pragma unroll
  for (int off = 32; off; off >>= 1) ss += __shfl_xor(ss, off);
  __shared__ float ps[4];
  if ((threadIdx.x & 63) == 0) ps[threadIdx.x >> 6] = ss;
  __syncthreads();
  float inv = rsqrtf((ps[0] + ps[1] + ps[2] + ps[3]) * (1.f / 1024.f) + 1e-5f);
  const float4 wv = *(const float4*)(w + threadIdx.x * 4);
  float4 o;
  o.x = v.x * inv * wv.x; o.y = v.y * inv * wv.y;
  o.z = v.z * inv * wv.z; o.w = v.w * inv * wv.w;
  *(float4*)(y + (size_t)t * 1024 + threadIdx.x * 4) = o;
}

// rmsnorm fine-final, dropping rows 0,1 of each chunk; packed[c][r*1024+d]
__global__ __launch_bounds__(256) void k_rmsnorm_pack(const float* __restrict__ x,
                                                      const float* __restrict__ w,
                                                      float* __restrict__ y) {
  int b = blockIdx.x;            // c*16 + r, 2048 blocks
  int c = b >> 4, r = b & 15;
  const float* xr = x + (size_t)(c * 18 + 2 + r) * 1024;
  const float4 v = *(const float4*)(xr + threadIdx.x * 4);
  float ss = v.x * v.x + v.y * v.y + v.z * v.z + v.w * v.w;
#pragma unroll
  for (int off = 32; off; off >>= 1) ss += __shfl_xor(ss, off);
  __shared__ float ps[4];
  if ((threadIdx.x & 63) == 0) ps[threadIdx.x >> 6] = ss;
  __syncthreads();
  float inv = rsqrtf((ps[0] + ps[1] + ps[2] + ps[3]) * (1.f / 1024.f) + 1e-5f);
  const float4 wv = *(const float4*)(w + threadIdx.x * 4);
  float4 o;
  o.x = v.x * inv * wv.x; o.y = v.y * inv * wv.y;
  o.z = v.z * inv * wv.z; o.w = v.w * inv * wv.w;
  *(float4*)(y + (size_t)b * 1024 + threadIdx.x * 4) = o;
}

// ---------------- rope in-place on q,k of qkv[T][3072]; pos = t % 18 ----------------
__global__ __launch_bounds__(256) void k_rope(float* __restrict__ qkv,
                                              const float* __restrict__ cosT,
                                              const float* __restrict__ sinT) {
  int t = blockIdx.x;
  int p = t % 18;
  float* row = qkv + (size_t)t * 3072;
#pragma unroll
  for (int i = 0; i < 4; ++i) {
    int it = threadIdx.x + i * 256;          // 1024 items: {q,k} x 16 heads x 32 pairs
    int s = it >> 9, rem = it & 511, h = rem >> 5, d = rem & 31;
    float* px = row + s * 1024 + h * 64 + d;
    float x1 = px[0], x2 = px[32];
    float cv = cosT[p * 64 + d], sv = sinT[p * 64 + d];
    px[0]  = x1 * cv - x2 * sv;
    px[32] = x2 * cv + x1 * sv;
  }
}

// ---------------- fine attention: full 18x18 softmax per (chunk, head) ----------------
__global__ __launch_bounds__(64) void k_attn_fine(const float* __restrict__ qkv,
                                                  float* __restrict__ out) {
  int blk = blockIdx.x;            // c*16 + h
  int c = blk >> 4, h = blk & 15;
  int lane = threadIdx.x;
  __shared__ float s[18][19];
  const float* base = qkv + (size_t)(c * 18) * 3072;
  for (int i = lane; i < 18 * 18; i += 64) {
    int qi = i / 18, ki = i - qi * 18;
    const float* qp = base + (size_t)qi * 3072 + h * 64;
    const float* kp = base + (size_t)ki * 3072 + 1024 + h * 64;
    float a = 0.f;
#pragma unroll
    for (int d = 0; d < 64; ++d) a += qp[d] * kp[d];
    s[qi][ki] = a * 0.125f;
  }
  __syncthreads();
  if (lane < 18) {
    float mx = -1e30f;
    for (int k = 0; k < 18; ++k) mx = fmaxf(mx, s[lane][k]);
    float sum = 0.f;
    for (int k = 0; k < 18; ++k) { float e = expf(s[lane][k] - mx); s[lane][k] = e; sum += e; }
    float inv = 1.f / sum;
    for (int k = 0; k < 18; ++k) s[lane][k] *= inv;
  }
  __syncthreads();
  for (int q = 0; q < 18; ++q) {
    float o = 0.f;
    for (int k = 0; k < 18; ++k)
      o += s[q][k] * base[(size_t)k * 3072 + 2048 + h * 64 + lane];
    out[(size_t)(c * 18 + q) * 1024 + h * 64 + lane] = o;
  }
}

// ---------------- decoder attention: keys = block-starts(<=q) ∪ own-block(<=q) ----------------
__global__ __launch_bounds__(64) void k_attn_dec(const float* __restrict__ qkv,
                                                 float* __restrict__ out) {
  int t = blockIdx.x, h = blockIdx.y, lane = threadIdx.x;
  __shared__ float sc[160];
  int bq = t / 18;
  int nstart = bq + 1;             // kv = 18*m, m in [0,bq]
  int nown = t - 18 * bq;          // kv = 18*bq+1 .. t
  int nk = nstart + nown;          // <= 145
  const float* qp = qkv + (size_t)t * 3072 + h * 64;
  for (int i = lane; i < nk; i += 64) {
    int kv = (i < nstart) ? 18 * i : 18 * bq + (i - nstart) + 1;
    const float* kp = qkv + (size_t)kv * 3072 + 1024 + h * 64;
    float a = 0.f;
#pragma unroll
    for (int d = 0; d < 64; ++d) a += qp[d] * kp[d];
    sc[i] = a * 0.125f;
  }
  __syncthreads();
  float mx = -1e30f;
  for (int i = lane; i < nk; i += 64) mx = fmaxf(mx, sc[i]);
#pragma unroll
  for (int off = 32; off; off >>= 1) mx = fmaxf(mx, __shfl_xor(mx, off));
  float sum = 0.f;
  for (int i = lane; i < nk; i += 64) { float e = expf(sc[i] - mx); sc[i] = e; sum += e; }
#pragma unroll
  for (int off = 32; off; off >>= 1) sum += __shfl_xor(sum, off);
  float inv = 1.f / sum;
  __syncthreads();
  float o = 0.f;
  for (int i = 0; i < nk; ++i) {
    int kv = (i < nstart) ? 18 * i : 18 * bq + (i - nstart) + 1;
    o += sc[i] * qkv[(size_t)kv * 3072 + 2048 + h * 64 + lane];
  }
  out[(size_t)t * 1024 + h * 64 + lane] = o * inv;
}

// ---------------- silu(g)*u, in place on g ----------------
__global__ void k_silumul(float* __restrict__ g, const float* __restrict__ u, int n4) {
  for (int i = blockIdx.x * blockDim.x + threadIdx.x; i < n4; i += gridDim.x * blockDim.x) {
    float4 a = ((const float4*)g)[i];
    float4 b = ((const float4*)u)[i];
    a.x = a.x / (1.f + expf(-a.x)) * b.x;
    a.y = a.y / (1.f + expf(-a.y)) * b.y;
    a.z = a.z / (1.f + expf(-a.z)) * b.z;
    a.w = a.w / (1.f + expf(-a.w)) * b.w;
    ((float4*)g)[i] = a;
  }
}

// ---------------- decoder input assembly ----------------
__global__ void k_assemble(const int* __restrict__ ids, const int* __restrict__ cspp,
                           const float* __restrict__ fx, const float* __restrict__ dummy_fx,
                           const float* __restrict__ sep, const float* __restrict__ wte,
                           float* __restrict__ xD) {
  int csp = fix_csp(cspp);
  for (int idx = blockIdx.x * 256 + threadIdx.x; idx < L_DEC * 1024; idx += gridDim.x * 256) {
    int t = idx >> 10, d = idx & 1023;
    float v;
    if (t == 2305)      v = sep[d];
    else if (t == 2304) v = fx[127 * 1024 + d];
    else {
      int k = t / 18, r = t - k * 18;
      if (r == 0)      v = (k == 0) ? dummy_fx[csp * 1024 + d] : fx[(k - 1) * 1024 + d];
      else if (r == 1) v = sep[d];
      else             v = wte[(size_t)ids[k * 16 + r - 2] * 1024 + d];
    }
    xD[idx] = v;
  }
}

extern "C" void kernel_launch(void* const* d_in, const int* in_sizes, int n_in,
                              void* d_out, int out_size, void* d_ws, size_t ws_size,
                              hipStream_t stream) {
  const int*   input_ids = (const int*)d_in[0];
  const int*   cspp      = (const int*)d_in[1];
  const float* f_wte     = (const float*)d_in[2];
  const float* f_pos     = (const float*)d_in[3];
  const float* f_adapt   = (const float*)d_in[4];
  const float* f_ln1     = (const float*)d_in[5];
  const float* f_ln2     = (const float*)d_in[6];
  const float* f_wqkv    = (const float*)d_in[7];
  const float* f_wo      = (const float*)d_in[8];
  const float* f_wg      = (const float*)d_in[9];
  const float* f_wu      = (const float*)d_in[10];
  const float* f_wd      = (const float*)d_in[11];
  const float* f_norm    = (const float*)d_in[12];
  const float* f_proj    = (const float*)d_in[13];
  const float* dummy_fx  = (const float*)d_in[14];
  const float* wte       = (const float*)d_in[15];
  const float* sep       = (const float*)d_in[16];
  const float* d_ln1     = (const float*)d_in[17];
  const float* d_ln2     = (const float*)d_in[18];
  const float* d_wqkv    = (const float*)d_in[19];
  const float* d_wo      = (const float*)d_in[20];
  const float* d_wg      = (const float*)d_in[21];
  const float* d_wu      = (const float*)d_in[22];
  const float* d_wd      = (const float*)d_in[23];
  const float* d_norm    = (const float*)d_in[24];
  const float* w_out     = (const float*)d_in[25];

  // ws: rope tables + bufH (must NOT alias d_out: final GEMM reads bufH while writing d_out)
  float* cosT = (float*)d_ws;
  float* sinT = cosT + 1152;
  float* bufH = sinT + 1152;                       // [2306][1024]

  // all other scratch inside d_out (f32 out: 73.79M floats; we use ~35.3M, head GEMM rewrites all)
  float* o      = (float*)d_out;
  float* xF     = o;                               // [2304][1024]
  float* xD     = xF + (size_t)T_FINE * 1024;      // [2306][1024]
  float* bufA   = xD + (size_t)L_DEC * 1024;       // [2306][1024]
  float* fx     = bufA + (size_t)L_DEC * 1024;     // [128][1024]
  float* packed = fx + 128 * 1024;                 // [128][16384]
  float* bufG   = packed + (size_t)128 * 16384;    // [2306][4096]
  float* bufU   = bufG + (size_t)L_DEC * 4096;     // [2306][4096]
  float* bufQKV = bufU + (size_t)L_DEC * 4096;     // [2306][3072], also split-K partials

#define GEMM(EPI, BT, Ap, Bp, Cp, M, N, K, S) \
  k_gemm<EPI, BT><<<dim3((N) / 128, ((M) + 127) / 128, (S)), 256, 0, stream>>>((Ap), (Bp), (Cp), (M), (N), (K), (K) / (S))

  k_rope_table<<<5, 256, 0, stream>>>(cosT, sinT);
  k_fine_embed<<<2048, 256, 0, stream>>>(input_ids, cspp, f_wte, f_pos, f_adapt, xF);

  // ---- fine (compressor) layers, all 128 chunks batched as 2304 rows ----
  for (int i = 0; i < 2; ++i) {
    k_rmsnorm<<<T_FINE, 256, 0, stream>>>(xF, f_ln1 + i * 1024, bufH);
    GEMM(0, 0, bufH, f_wqkv + (size_t)i * 1024 * 3072, bufQKV, T_FINE, 3072, 1024, 1);
    k_rope<<<T_FINE, 256, 0, stream>>>(bufQKV, cosT, sinT);
    k_attn_fine<<<2048, 64, 0, stream>>>(bufQKV, bufA);
    GEMM(1, 0, bufA, f_wo + (size_t)i * 1024 * 1024, xF, T_FINE, 1024, 1024, 1);
    k_rmsnorm<<<T_FINE, 256, 0, stream>>>(xF, f_ln2 + i * 1024, bufH);
    GEMM(0, 0, bufH, f_wg + (size_t)i * 1024 * 4096, bufG, T_FINE, 4096, 1024, 1);
    GEMM(0, 0, bufH, f_wu + (size_t)i * 1024 * 4096, bufU, T_FINE, 4096, 1024, 1);
    k_silumul<<<2048, 256, 0, stream>>>(bufG, bufU, T_FINE * 1024);
    GEMM(1, 0, bufG, f_wd + (size_t)i * 4096 * 1024, xF, T_FINE, 1024, 4096, 1);
  }

  // ---- fx = rmsnorm-packed @ f_proj^T  (split-K=16, deterministic partials+reduce) ----
  k_rmsnorm_pack<<<2048, 256, 0, stream>>>(xF, f_norm, packed);
  GEMM(0, 1, packed, f_proj, bufQKV, 128, 1024, 16384, 16);
  k_reduce16<<<512, 256, 0, stream>>>(bufQKV, fx);

  // ---- decoder ----
  k_assemble<<<2048, 256, 0, stream>>>(input_ids, cspp, fx, dummy_fx, sep, wte, xD);
  for (int i = 0; i < 2; ++i) {
    k_rmsnorm<<<L_DEC, 256, 0, stream>>>(xD, d_ln1 + i * 1024, bufH);
    GEMM(0, 0, bufH, d_wqkv + (size_t)i * 1024 * 3072, bufQKV, L_DEC, 3072, 1024, 1);
    k_rope<<<L_DEC, 256, 0, stream>>>(bufQKV, cosT, sinT);
    k_attn_dec<<<dim3(L_DEC, 16), 64, 0, stream>>>(bufQKV, bufA);
    GEMM(1, 0, bufA, d_wo + (size_t)i * 1024 * 1024, xD, L_DEC, 1024, 1024, 1);
    k_rmsnorm<<<L_DEC, 256, 0, stream>>>(xD, d_ln2 + i * 1024, bufH);
    GEMM(0, 0, bufH, d_wg + (size_t)i * 1024 * 4096, bufG, L_DEC, 4096, 1024, 1);
    GEMM(0, 0, bufH, d_wu + (size_t)i * 1024 * 4096, bufU, L_DEC, 4096, 1024, 1);
    k_silumul<<<2048, 256, 0, stream>>>(bufG, bufU, L_DEC * 1024);
    GEMM(1, 0, bufG, d_wd + (size_t)i * 4096 * 1024, xD, L_DEC, 1024, 4096, 1);
  }

  // ---- head: out = rmsnorm(xD) @ w_out^T (writes ALL of d_out, killing scratch) ----
  k_rmsnorm<<<L_DEC, 256, 0, stream>>>(xD, d_norm, bufH);
  GEMM(0, 1, bufH, w_out, o, L_DEC, 32000, 1024, 1);
#undef GEMM
}

// Round 2
// 2003.117 us; speedup vs baseline: 2.2431x; 2.2431x over previous
//
#include <hip/hip_runtime.h>
#include <math.h>

#define L_DEC 2306
#define MPAD 2432      // 19*128, decoder rows padded
#define T_FINE 2304    // 18*128, exact

typedef float f32x4 __attribute__((ext_vector_type(4)));
typedef __bf16 bf16x8 __attribute__((ext_vector_type(8)));
typedef unsigned short u16;
typedef unsigned short us4 __attribute__((ext_vector_type(4)));
typedef unsigned short us8 __attribute__((ext_vector_type(8)));

#define GLOAD16(g, l) __builtin_amdgcn_global_load_lds( \
    (const __attribute__((address_space(1))) unsigned int*)(g), \
    (__attribute__((address_space(3))) unsigned int*)(l), 16, 0, 0)

__device__ __forceinline__ u16 f2bf(float f) {
  unsigned u = __float_as_uint(f);
  u += 0x7fffu + ((u >> 16) & 1u);   // RNE
  return (u16)(u >> 16);
}

__device__ __forceinline__ int fix_csp(const int* p) {
  int c = p[0];
  if ((unsigned)c <= 4u) return c;
  float f = __uint_as_float((unsigned)c);
  int c2 = (int)f;
  return ((unsigned)c2 <= 4u) ? c2 : 4;
}

// ---------------- MFMA GEMM, m97 structure: A[Mpad][K] bf16, B[N][K] bf16 ----------------
// EPI=0: store (blockIdx.z split-K partial planes of Mstore*N). EPI=1: C += acc.
template<int EPI>
__global__ __launch_bounds__(256) void k_gemm_bt(const u16* __restrict__ A,
                                                 const u16* __restrict__ B,
                                                 float* __restrict__ C,
                                                 int N, int K, int Mstore, int kchunk)
{
  __shared__ u16 As[4096];   // [128 rows][32 k] linear
  __shared__ u16 Bs[4096];
  const int tid = threadIdx.x;
  const int bm = blockIdx.y * 128, bn = blockIdx.x * 128;
  const int k0 = blockIdx.z * kchunk;
  const int w = tid >> 6, lane = tid & 63;
  const int wm = (w >> 1) * 64, wn = (w & 1) * 64;
  const int lr = lane & 15, kh = lane >> 4;
  const int r0 = tid >> 2, kc0 = (tid & 3) * 8;

  const u16* ga = A + (size_t)(bm + r0) * K + k0 + kc0;
  const u16* gb = B + (size_t)(bn + r0) * K + k0 + kc0;
  u16* la = &As[tid * 8];
  u16* lb = &Bs[tid * 8];
  const size_t rstep = (size_t)64 * K;

  f32x4 acc[4][4] = {};
  for (int kk = 0; kk < kchunk; kk += 32) {
    GLOAD16(ga, la); GLOAD16(ga + rstep, la + 2048);
    GLOAD16(gb, lb); GLOAD16(gb + rstep, lb + 2048);
    ga += 32; gb += 32;
    __syncthreads();            // drains vmcnt -> LDS tiles ready
    bf16x8 af[4], bfr[4];
#pragma unroll
    for (int m = 0; m < 4; ++m)
      af[m] = *(const bf16x8*)&As[(wm + m * 16 + lr) * 32 + kh * 8];
#pragma unroll
    for (int n = 0; n < 4; ++n)
      bfr[n] = *(const bf16x8*)&Bs[(wn + n * 16 + lr) * 32 + kh * 8];
#pragma unroll
    for (int m = 0; m < 4; ++m)
#pragma unroll
      for (int n = 0; n < 4; ++n)
        acc[m][n] = __builtin_amdgcn_mfma_f32_16x16x32_bf16(af[m], bfr[n], acc[m][n], 0, 0, 0);
    __syncthreads();
  }

  float* Cz = C + (size_t)blockIdx.z * Mstore * N;
#pragma unroll
  for (int m = 0; m < 4; ++m) {
    int gr0 = bm + wm + m * 16 + kh * 4;
#pragma unroll
    for (int n = 0; n < 4; ++n) {
      int gc = bn + wn + n * 16 + lr;
#pragma unroll
      for (int r = 0; r < 4; ++r) {
        int gr = gr0 + r;
        if (gr < Mstore) {
          size_t off = (size_t)gr * N + gc;
          if (EPI == 0) Cz[off] = acc[m][n][r];
          else          C[off] += acc[m][n][r];
        }
      }
    }
  }
}

// Head fallback when ws can't hold bf16 w_out: A bf16 via global_load_lds, B f32 converted in-kernel.
__global__ __launch_bounds__(256) void k_gemm_hf(const u16* __restrict__ A,
                                                 const float* __restrict__ B,
                                                 float* __restrict__ C,
                                                 int N, int K, int Mstore)
{
  __shared__ u16 As[4096];
  __shared__ u16 Bs[4096];
  const int tid = threadIdx.x;
  const int bm = blockIdx.y * 128, bn = blockIdx.x * 128;
  const int w = tid >> 6, lane = tid & 63;
  const int wm = (w >> 1) * 64, wn = (w & 1) * 64;
  const int lr = lane & 15, kh = lane >> 4;
  const int r0 = tid >> 2, kc0 = (tid & 3) * 8;
  const u16* ga = A + (size_t)(bm + r0) * K + kc0;
  u16* la = &As[tid * 8];
  const size_t rstep = (size_t)64 * K;

  f32x4 acc[4][4] = {};
  for (int kk = 0; kk < K; kk += 32) {
    GLOAD16(ga, la); GLOAD16(ga + rstep, la + 2048);
    ga += 32;
#pragma unroll
    for (int p = 0; p < 4; ++p) {
      int e = tid + p * 256;
      int row = e >> 3, kc = (e & 7) * 4;
      float4 v = *(const float4*)(B + (size_t)(bn + row) * K + kk + kc);
      us4 pk; pk[0] = f2bf(v.x); pk[1] = f2bf(v.y); pk[2] = f2bf(v.z); pk[3] = f2bf(v.w);
      *(us4*)&Bs[row * 32 + kc] = pk;
    }
    __syncthreads();
    bf16x8 af[4], bfr[4];
#pragma unroll
    for (int m = 0; m < 4; ++m)
      af[m] = *(const bf16x8*)&As[(wm + m * 16 + lr) * 32 + kh * 8];
#pragma unroll
    for (int n = 0; n < 4; ++n)
      bfr[n] = *(const bf16x8*)&Bs[(wn + n * 16 + lr) * 32 + kh * 8];
#pragma unroll
    for (int m = 0; m < 4; ++m)
#pragma unroll
      for (int n = 0; n < 4; ++n)
        acc[m][n] = __builtin_amdgcn_mfma_f32_16x16x32_bf16(af[m], bfr[n], acc[m][n], 0, 0, 0);
    __syncthreads();
  }
#pragma unroll
  for (int m = 0; m < 4; ++m) {
    int gr0 = bm + wm + m * 16 + kh * 4;
#pragma unroll
    for (int n = 0; n < 4; ++n) {
      int gc = bn + wn + n * 16 + lr;
#pragma unroll
      for (int r = 0; r < 4; ++r) {
        int gr = gr0 + r;
        if (gr < Mstore) C[(size_t)gr * N + gc] = acc[m][n][r];
      }
    }
  }
}

// ---------------- weight transpose-convert: W[K,N] f32 -> Wt[N,K] bf16 ----------------
__global__ __launch_bounds__(256) void k_wt(const float* __restrict__ W, u16* __restrict__ Wt,
                                            int K, int N) {
  __shared__ u16 t[64][80];
  int n0 = blockIdx.x * 64, k0 = blockIdx.y * 64;
#pragma unroll
  for (int p = 0; p < 4; ++p) {
    int id = threadIdx.x + p * 256;
    int row = id >> 4, c4 = (id & 15) * 4;
    float4 v = *(const float4*)(W + (size_t)(k0 + row) * N + n0 + c4);
    t[c4 + 0][row] = f2bf(v.x);
    t[c4 + 1][row] = f2bf(v.y);
    t[c4 + 2][row] = f2bf(v.z);
    t[c4 + 3][row] = f2bf(v.w);
  }
  __syncthreads();
#pragma unroll
  for (int p = 0; p < 2; ++p) {
    int id = threadIdx.x + p * 256;
    int row = id >> 3, c8 = (id & 7) * 8;
    *(us8*)(Wt + (size_t)(n0 + row) * K + k0 + c8) = *(const us8*)&t[row][c8];
  }
}

// ---------------- flat f32 -> bf16 convert ----------------
__global__ void k_cvt(const float* __restrict__ x, u16* __restrict__ y, int n4) {
  for (int i = blockIdx.x * 256 + threadIdx.x; i < n4; i += gridDim.x * 256) {
    float4 v = ((const float4*)x)[i];
    us4 p; p[0] = f2bf(v.x); p[1] = f2bf(v.y); p[2] = f2bf(v.z); p[3] = f2bf(v.w);
    ((us4*)y)[i] = p;
  }
}

__global__ void k_reduce16(const float* __restrict__ p, float* __restrict__ o) {
  int i = blockIdx.x * 256 + threadIdx.x;
  if (i >= 128 * 1024) return;
  float s = 0.f;
#pragma unroll
  for (int z = 0; z < 16; ++z) s += p[z * 131072 + i];
  o[i] = s;
}

__global__ void k_rope_table(float* __restrict__ cosT, float* __restrict__ sinT) {
  int i = blockIdx.x * blockDim.x + threadIdx.x;
  if (i >= 18 * 64) return;
  int p = i >> 6, d = i & 63;
  float theta = powf(10000.f, -(float)(d & 31) / 32.f);
  float ang = (float)p * theta;
  cosT[i] = cosf(ang);
  sinT[i] = sinf(ang);
}

__global__ void k_fine_embed(const int* __restrict__ ids, const int* __restrict__ cspp,
                             const float* __restrict__ f_wte, const float* __restrict__ f_pos,
                             const float* __restrict__ f_adapt, float* __restrict__ xF) {
  int csp = fix_csp(cspp);
  for (int idx = blockIdx.x * 256 + threadIdx.x; idx < T_FINE * 1024; idx += gridDim.x * 256) {
    int r = idx >> 10, d = idx & 1023;
    int c = r / 18, j = r - c * 18;
    float v;
    if (j == 0)      v = f_adapt[csp * 1024 + d];
    else if (j == 1) v = f_pos[c * 1024 + d];
    else             v = f_wte[(size_t)ids[c * 16 + j - 2] * 1024 + d];
    xF[idx] = v;
  }
}

// ---------------- rmsnorm -> bf16 out ----------------
__global__ __launch_bounds__(256) void k_rmsnorm_bf(const float* __restrict__ x,
                                                    const float* __restrict__ w,
                                                    u16* __restrict__ y) {
  int t = blockIdx.x;
  const float4 v = *(const float4*)(x + (size_t)t * 1024 + threadIdx.x * 4);
  float ss = v.x * v.x + v.y * v.y + v.z * v.z + v.w * v.w;
#pragma unroll
  for (int off = 32; off; off >>= 1) ss += __shfl_xor(ss, off);
  __shared__ float ps[4];
  if ((threadIdx.x & 63) == 0) ps[threadIdx.x >> 6] = ss;
  __syncthreads();
  float inv = rsqrtf((ps[0] + ps[1] + ps[2] + ps[3]) * (1.f / 1024.f) + 1e-5f);
  const float4 wv = *(const float4*)(w + threadIdx.x * 4);
  us4 o;
  o[0] = f2bf(v.x * inv * wv.x); o[1] = f2bf(v.y * inv * wv.y);
  o[2] = f2bf(v.z * inv * wv.z); o[3] = f2bf(v.w * inv * wv.w);
  *(us4*)(y + (size_t)t * 1024 + threadIdx.x * 4) = o;
}

// rmsnorm fine-final, drop rows 0,1 per chunk -> packed bf16 [128][16384]
__global__ __launch_bounds__(256) void k_rmsnorm_pack_bf(const float* __restrict__ x,
                                                         const float* __restrict__ w,
                                                         u16* __restrict__ y) {
  int b = blockIdx.x;            // c*16 + r
  int c = b >> 4, r = b & 15;
  const float* xr = x + (size_t)(c * 18 + 2 + r) * 1024;
  const float4 v = *(const float4*)(xr + threadIdx.x * 4);
  float ss = v.x * v.x + v.y * v.y + v.z * v.z + v.w * v.w;
#pragma unroll
  for (int off = 32; off; off >>= 1) ss += __shfl_xor(ss, off);
  __shared__ float ps[4];
  if ((threadIdx.x & 63) == 0) ps[threadIdx.x >> 6] = ss;
  __syncthreads();
  float inv = rsqrtf((ps[0] + ps[1] + ps[2] + ps[3]) * (1.f / 1024.f) + 1e-5f);
  const float4 wv = *(const float4*)(w + threadIdx.x * 4);
  us4 o;
  o[0] = f2bf(v.x * inv * wv.x); o[1] = f2bf(v.y * inv * wv.y);
  o[2] = f2bf(v.z * inv * wv.z); o[3] = f2bf(v.w * inv * wv.w);
  *(us4*)(y + (size_t)b * 1024 + threadIdx.x * 4) = o;
}

// ---------------- rope in-place on q,k of qkv[T][3072] f32; pos = t % 18 ----------------
__global__ __launch_bounds__(256) void k_rope(float* __restrict__ qkv,
                                              const float* __restrict__ cosT,
                                              const float* __restrict__ sinT) {
  int t = blockIdx.x;
  int p = t % 18;
  float* row = qkv + (size_t)t * 3072;
#pragma unroll
  for (int i = 0; i < 4; ++i) {
    int it = threadIdx.x + i * 256;
    int s = it >> 9, rem = it & 511, h = rem >> 5, d = rem & 31;
    float* px = row + s * 1024 + h * 64 + d;
    float x1 = px[0], x2 = px[32];
    float cv = cosT[p * 64 + d], sv = sinT[p * 64 + d];
    px[0]  = x1 * cv - x2 * sv;
    px[32] = x2 * cv + x1 * sv;
  }
}

// ---------------- fine attention (18x18 dense) -> bf16 out ----------------
__global__ __launch_bounds__(64) void k_attn_fine(const float* __restrict__ qkv,
                                                  u16* __restrict__ out) {
  int blk = blockIdx.x;            // c*16 + h
  int c = blk >> 4, h = blk & 15;
  int lane = threadIdx.x;
  __shared__ float s[18][19];
  const float* base = qkv + (size_t)(c * 18) * 3072;
  for (int i = lane; i < 18 * 18; i += 64) {
    int qi = i / 18, ki = i - qi * 18;
    const float* qp = base + (size_t)qi * 3072 + h * 64;
    const float* kp = base + (size_t)ki * 3072 + 1024 + h * 64;
    float a = 0.f;
#pragma unroll
    for (int d = 0; d < 64; ++d) a += qp[d] * kp[d];
    s[qi][ki] = a * 0.125f;
  }
  __syncthreads();
  if (lane < 18) {
    float mx = -1e30f;
    for (int k = 0; k < 18; ++k) mx = fmaxf(mx, s[lane][k]);
    float sum = 0.f;
    for (int k = 0; k < 18; ++k) { float e = expf(s[lane][k] - mx); s[lane][k] = e; sum += e; }
    float inv = 1.f / sum;
    for (int k = 0; k < 18; ++k) s[lane][k] *= inv;
  }
  __syncthreads();
  for (int q = 0; q < 18; ++q) {
    float o = 0.f;
    for (int k = 0; k < 18; ++k)
      o += s[q][k] * base[(size_t)k * 3072 + 2048 + h * 64 + lane];
    out[(size_t)(c * 18 + q) * 1024 + h * 64 + lane] = f2bf(o);
  }
}

// ---------------- decoder attention -> bf16 out ----------------
__global__ __launch_bounds__(64) void k_attn_dec(const float* __restrict__ qkv,
                                                 u16* __restrict__ out) {
  int t = blockIdx.x, h = blockIdx.y, lane = threadIdx.x;
  __shared__ float sc[160];
  int bq = t / 18;
  int nstart = bq + 1;
  int nown = t - 18 * bq;
  int nk = nstart + nown;
  const float* qp = qkv + (size_t)t * 3072 + h * 64;
  for (int i = lane; i < nk; i += 64) {
    int kv = (i < nstart) ? 18 * i : 18 * bq + (i - nstart) + 1;
    const float* kp = qkv + (size_t)kv * 3072 + 1024 + h * 64;
    float a = 0.f;
#pragma unroll
    for (int d = 0; d < 64; ++d) a += qp[d] * kp[d];
    sc[i] = a * 0.125f;
  }
  __syncthreads();
  float mx = -1e30f;
  for (int i = lane; i < nk; i += 64) mx = fmaxf(mx, sc[i]);
#pragma unroll
  for (int off = 32; off; off >>= 1) mx = fmaxf(mx, __shfl_xor(mx, off));
  float sum = 0.f;
  for (int i = lane; i < nk; i += 64) { float e = expf(sc[i] - mx); sc[i] = e; sum += e; }
#pragma unroll
  for (int off = 32; off; off >>= 1) sum += __shfl_xor(sum, off);
  float inv = 1.f / sum;
  __syncthreads();
  float o = 0.f;
  for (int i = 0; i < nk; ++i) {
    int kv = (i < nstart) ? 18 * i : 18 * bq + (i - nstart) + 1;
    o += sc[i] * qkv[(size_t)kv * 3072 + 2048 + h * 64 + lane];
  }
  out[(size_t)t * 1024 + h * 64 + lane] = f2bf(o * inv);
}

// ---------------- silu(g)*u -> bf16 out ----------------
__global__ void k_silumul_bf(const float* __restrict__ g, const float* __restrict__ u,
                             u16* __restrict__ y, int n4) {
  for (int i = blockIdx.x * 256 + threadIdx.x; i < n4; i += gridDim.x * 256) {
    float4 a = ((const float4*)g)[i];
    float4 b = ((const float4*)u)[i];
    us4 o;
    o[0] = f2bf(a.x / (1.f + expf(-a.x)) * b.x);
    o[1] = f2bf(a.y / (1.f + expf(-a.y)) * b.y);
    o[2] = f2bf(a.z / (1.f + expf(-a.z)) * b.z);
    o[3] = f2bf(a.w / (1.f + expf(-a.w)) * b.w);
    ((us4*)y)[i] = o;
  }
}

// ---------------- decoder input assembly (zeroes pad rows 2306..2431) ----------------
__global__ void k_assemble(const int* __restrict__ ids, const int* __restrict__ cspp,
                           const float* __restrict__ fx, const float* __restrict__ dummy_fx,
                           const float* __restrict__ sep, const float* __restrict__ wte,
                           float* __restrict__ xD) {
  int csp = fix_csp(cspp);
  for (int idx = blockIdx.x * 256 + threadIdx.x; idx < MPAD * 1024; idx += gridDim.x * 256) {
    int t = idx >> 10, d = idx & 1023;
    float v;
    if (t >= L_DEC)     v = 0.f;
    else if (t == 2305) v = sep[d];
    else if (t == 2304) v = fx[127 * 1024 + d];
    else {
      int k = t / 18, r = t - k * 18;
      if (r == 0)      v = (k == 0) ? dummy_fx[csp * 1024 + d] : fx[(k - 1) * 1024 + d];
      else if (r == 1) v = sep[d];
      else             v = wte[(size_t)ids[k * 16 + r - 2] * 1024 + d];
    }
    xD[idx] = v;
  }
}

extern "C" void kernel_launch(void* const* d_in, const int* in_sizes, int n_in,
                              void* d_out, int out_size, void* d_ws, size_t ws_size,
                              hipStream_t stream) {
  const int*   input_ids = (const int*)d_in[0];
  const int*   cspp      = (const int*)d_in[1];
  const float* f_wte     = (const float*)d_in[2];
  const float* f_pos     = (const float*)d_in[3];
  const float* f_adapt   = (const float*)d_in[4];
  const float* f_ln1     = (const float*)d_in[5];
  const float* f_ln2     = (const float*)d_in[6];
  const float* f_wqkv    = (const float*)d_in[7];
  const float* f_wo      = (const float*)d_in[8];
  const float* f_wg      = (const float*)d_in[9];
  const float* f_wu      = (const float*)d_in[10];
  const float* f_wd      = (const float*)d_in[11];
  const float* f_norm    = (const float*)d_in[12];
  const float* f_proj    = (const float*)d_in[13];
  const float* dummy_fx  = (const float*)d_in[14];
  const float* wte       = (const float*)d_in[15];
  const float* sep       = (const float*)d_in[16];
  const float* d_ln1     = (const float*)d_in[17];
  const float* d_ln2     = (const float*)d_in[18];
  const float* d_wqkv    = (const float*)d_in[19];
  const float* d_wo      = (const float*)d_in[20];
  const float* d_wg      = (const float*)d_in[21];
  const float* d_wu      = (const float*)d_in[22];
  const float* d_wd      = (const float*)d_in[23];
  const float* d_norm    = (const float*)d_in[24];
  const float* w_out     = (const float*)d_in[25];

  // ---- d_ws: rope tables + bufH (bf16) + (if room) bf16 w_out ----
  float* cosT = (float*)d_ws;
  float* sinT = cosT + 1152;
  u16*   bufH = (u16*)(sinT + 1152);                 // [MPAD][1024] bf16
  u16*   w_outb = bufH + (size_t)MPAD * 1024;        // [32000][1024] bf16 (optional)
  const size_t WS_NEED = 2 * 1152 * 4 + (size_t)MPAD * 1024 * 2 + (size_t)32000 * 1024 * 2;
  const bool big_ws = ws_size >= WS_NEED;

  // ---- d_out scratch (head GEMM reads only ws buffers, so it may overwrite all of this) ----
  float* o       = (float*)d_out;
  float* xF      = o;                                   // [2304][1024] f32
  float* xD      = xF + (size_t)T_FINE * 1024;          // [MPAD][1024] f32
  float* fx      = xD + (size_t)MPAD * 1024;            // [128][1024] f32
  float* bufQKV  = fx + 128 * 1024;                     // [MPAD][3072] f32 (also split-K partials)
  float* bufG    = bufQKV + (size_t)MPAD * 3072;        // [MPAD][4096] f32
  float* bufU    = bufG + (size_t)MPAD * 4096;          // [MPAD][4096] f32
  u16*   bufA    = (u16*)(bufU + (size_t)MPAD * 4096);  // [MPAD][1024] bf16
  u16*   bufGb   = bufA + (size_t)MPAD * 1024;          // [MPAD][4096] bf16
  u16*   packedb = bufGb + (size_t)MPAD * 4096;         // [128][16384] bf16
  u16*   Wt      = packedb + (size_t)128 * 16384;       // [<=4096][<=4096] bf16 staging
  u16*   projb   = Wt + (size_t)4096 * 1024;            // [1024][16384] bf16

#define GEMM_BT(EPI, Ap, Bp, Cp, Mpad, N, K, Mstore, S) \
  k_gemm_bt<EPI><<<dim3((N) / 128, (Mpad) / 128, (S)), 256, 0, stream>>>((Ap), (Bp), (Cp), (N), (K), (Mstore), (K) / (S))

  k_rope_table<<<5, 256, 0, stream>>>(cosT, sinT);
  k_fine_embed<<<2048, 256, 0, stream>>>(input_ids, cspp, f_wte, f_pos, f_adapt, xF);

  // ---- fine (compressor) layers: M = 2304 exact ----
  for (int i = 0; i < 2; ++i) {
    k_rmsnorm_bf<<<T_FINE, 256, 0, stream>>>(xF, f_ln1 + i * 1024, bufH);
    k_wt<<<dim3(48, 16), 256, 0, stream>>>(f_wqkv + (size_t)i * 1024 * 3072, Wt, 1024, 3072);
    GEMM_BT(0, bufH, Wt, bufQKV, T_FINE, 3072, 1024, T_FINE, 1);
    k_rope<<<T_FINE, 256, 0, stream>>>(bufQKV, cosT, sinT);
    k_attn_fine<<<2048, 64, 0, stream>>>(bufQKV, bufA);
    k_wt<<<dim3(16, 16), 256, 0, stream>>>(f_wo + (size_t)i * 1024 * 1024, Wt, 1024, 1024);
    GEMM_BT(1, bufA, Wt, xF, T_FINE, 1024, 1024, T_FINE, 1);
    k_rmsnorm_bf<<<T_FINE, 256, 0, stream>>>(xF, f_ln2 + i * 1024, bufH);
    k_wt<<<dim3(64, 16), 256, 0, stream>>>(f_wg + (size_t)i * 1024 * 4096, Wt, 1024, 4096);
    GEMM_BT(0, bufH, Wt, bufG, T_FINE, 4096, 1024, T_FINE, 1);
    k_wt<<<dim3(64, 16), 256, 0, stream>>>(f_wu + (size_t)i * 1024 * 4096, Wt, 1024, 4096);
    GEMM_BT(0, bufH, Wt, bufU, T_FINE, 4096, 1024, T_FINE, 1);
    k_silumul_bf<<<2048, 256, 0, stream>>>(bufG, bufU, bufGb, T_FINE * 1024);
    k_wt<<<dim3(16, 64), 256, 0, stream>>>(f_wd + (size_t)i * 4096 * 1024, Wt, 4096, 1024);
    GEMM_BT(1, bufGb, Wt, xF, T_FINE, 1024, 4096, T_FINE, 1);
  }

  // ---- fx = packed @ f_proj^T : f_proj is [1024][16384] = [N][K] already; split-K 16 ----
  k_rmsnorm_pack_bf<<<2048, 256, 0, stream>>>(xF, f_norm, packedb);
  k_cvt<<<2048, 256, 0, stream>>>(f_proj, projb, 1024 * 16384 / 4);
  GEMM_BT(0, packedb, projb, bufQKV, 128, 1024, 16384, 128, 16);
  k_reduce16<<<512, 256, 0, stream>>>(bufQKV, fx);

  // ---- decoder: M padded to 2432 ----
  k_assemble<<<2048, 256, 0, stream>>>(input_ids, cspp, fx, dummy_fx, sep, wte, xD);
  for (int i = 0; i < 2; ++i) {
    k_rmsnorm_bf<<<MPAD, 256, 0, stream>>>(xD, d_ln1 + i * 1024, bufH);
    k_wt<<<dim3(48, 16), 256, 0, stream>>>(d_wqkv + (size_t)i * 1024 * 3072, Wt, 1024, 3072);
    GEMM_BT(0, bufH, Wt, bufQKV, MPAD, 3072, 1024, MPAD, 1);
    k_rope<<<L_DEC, 256, 0, stream>>>(bufQKV, cosT, sinT);
    k_attn_dec<<<dim3(L_DEC, 16), 64, 0, stream>>>(bufQKV, bufA);
    k_wt<<<dim3(16, 16), 256, 0, stream>>>(d_wo + (size_t)i * 1024 * 1024, Wt, 1024, 1024);
    GEMM_BT(1, bufA, Wt, xD, MPAD, 1024, 1024, MPAD, 1);
    k_rmsnorm_bf<<<MPAD, 256, 0, stream>>>(xD, d_ln2 + i * 1024, bufH);
    k_wt<<<dim3(64, 16), 256, 0, stream>>>(d_wg + (size_t)i * 1024 * 4096, Wt, 1024, 4096);
    GEMM_BT(0, bufH, Wt, bufG, MPAD, 4096, 1024, MPAD, 1);
    k_wt<<<dim3(64, 16), 256, 0, stream>>>(d_wu + (size_t)i * 1024 * 4096, Wt, 1024, 4096);
    GEMM_BT(0, bufH, Wt, bufU, MPAD, 4096, 1024, MPAD, 1);
    k_silumul_bf<<<2048, 256, 0, stream>>>(bufG, bufU, bufGb, MPAD * 1024);
    k_wt<<<dim3(16, 64), 256, 0, stream>>>(d_wd + (size_t)i * 4096 * 1024, Wt, 4096, 1024);
    GEMM_BT(1, bufGb, Wt, xD, MPAD, 1024, 4096, MPAD, 1);
  }

  // ---- head: out = rmsnorm(xD) @ w_out^T ; w_out is [32000][1024] = [N][K] already ----
  k_rmsnorm_bf<<<MPAD, 256, 0, stream>>>(xD, d_norm, bufH);
  if (big_ws) {
    k_cvt<<<2048, 256, 0, stream>>>(w_out, w_outb, 32000 * 1024 / 4);
    GEMM_BT(0, bufH, w_outb, o, MPAD, 32000, 1024, L_DEC, 1);
  } else {
    k_gemm_hf<<<dim3(250, 19), 256, 0, stream>>>(bufH, w_out, o, 32000, 1024, L_DEC);
  }
#undef GEMM_BT
}

// Round 3
// 1763.898 us; speedup vs baseline: 2.5473x; 1.1356x over previous
//
#include <hip/hip_runtime.h>
#include <math.h>

#define L_DEC 2306
#define MPAD 2432      // 19*128, decoder rows padded
#define T_FINE 2304    // 18*128, exact

typedef float f32x4 __attribute__((ext_vector_type(4)));
typedef __bf16 bf16x8 __attribute__((ext_vector_type(8)));
typedef unsigned short u16;
typedef unsigned short us4 __attribute__((ext_vector_type(4)));
typedef unsigned short us8 __attribute__((ext_vector_type(8)));

#define GLOAD16(g, l) __builtin_amdgcn_global_load_lds( \
    (const __attribute__((address_space(1))) unsigned int*)(g), \
    (__attribute__((address_space(3))) unsigned int*)(l), 16, 0, 0)

__device__ __forceinline__ u16 f2bf(float f) {
  unsigned u = __float_as_uint(f);
  u += 0x7fffu + ((u >> 16) & 1u);   // RNE
  return (u16)(u >> 16);
}

__device__ __forceinline__ int fix_csp(const int* p) {
  int c = p[0];
  if ((unsigned)c <= 4u) return c;
  float f = __uint_as_float((unsigned)c);
  int c2 = (int)f;
  return ((unsigned)c2 <= 4u) ? c2 : 4;
}

// ---------------- MFMA GEMM, m97 structure + XCD swizzle: A[Mpad][K] bf16, B[N][K] bf16 ----
// EPI=0: store (blockIdx.z split-K partial planes of Mstore*N). EPI=1: C += acc.
template<int EPI>
__global__ __launch_bounds__(256) void k_gemm_bt(const u16* __restrict__ A,
                                                 const u16* __restrict__ B,
                                                 float* __restrict__ C,
                                                 int N, int K, int Mstore, int kchunk)
{
  __shared__ u16 As[4096];   // [128 rows][32 k] linear
  __shared__ u16 Bs[4096];
  const int tid = threadIdx.x;
  // XCD-aware bijective swizzle (m204) over the x*y tile space; z (split-K) untouched.
  const int gx = gridDim.x;
  const int nwg = gx * gridDim.y;
  const int orig = blockIdx.y * gx + blockIdx.x;
  const int q8 = nwg >> 3, r8 = nwg & 7;
  const int xcd = orig & 7, idx8 = orig >> 3;
  const int wg = (xcd < r8 ? xcd * (q8 + 1) : r8 * (q8 + 1) + (xcd - r8) * q8) + idx8;
  const int bm = (wg / gx) * 128, bn = (wg % gx) * 128;
  const int k0 = blockIdx.z * kchunk;
  const int w = tid >> 6, lane = tid & 63;
  const int wm = (w >> 1) * 64, wn = (w & 1) * 64;
  const int lr = lane & 15, kh = lane >> 4;
  const int r0 = tid >> 2, kc0 = (tid & 3) * 8;

  const u16* ga = A + (size_t)(bm + r0) * K + k0 + kc0;
  const u16* gb = B + (size_t)(bn + r0) * K + k0 + kc0;
  u16* la = &As[tid * 8];
  u16* lb = &Bs[tid * 8];
  const size_t rstep = (size_t)64 * K;

  f32x4 acc[4][4] = {};
  for (int kk = 0; kk < kchunk; kk += 32) {
    GLOAD16(ga, la); GLOAD16(ga + rstep, la + 2048);
    GLOAD16(gb, lb); GLOAD16(gb + rstep, lb + 2048);
    ga += 32; gb += 32;
    __syncthreads();            // drains vmcnt -> LDS tiles ready
    bf16x8 af[4], bfr[4];
#pragma unroll
    for (int m = 0; m < 4; ++m)
      af[m] = *(const bf16x8*)&As[(wm + m * 16 + lr) * 32 + kh * 8];
#pragma unroll
    for (int n = 0; n < 4; ++n)
      bfr[n] = *(const bf16x8*)&Bs[(wn + n * 16 + lr) * 32 + kh * 8];
#pragma unroll
    for (int m = 0; m < 4; ++m)
#pragma unroll
      for (int n = 0; n < 4; ++n)
        acc[m][n] = __builtin_amdgcn_mfma_f32_16x16x32_bf16(af[m], bfr[n], acc[m][n], 0, 0, 0);
    __syncthreads();
  }

  float* Cz = C + (size_t)blockIdx.z * Mstore * N;
#pragma unroll
  for (int m = 0; m < 4; ++m) {
    int gr0 = bm + wm + m * 16 + kh * 4;
#pragma unroll
    for (int n = 0; n < 4; ++n) {
      int gc = bn + wn + n * 16 + lr;
#pragma unroll
      for (int r = 0; r < 4; ++r) {
        int gr = gr0 + r;
        if (gr < Mstore) {
          size_t off = (size_t)gr * N + gc;
          if (EPI == 0) Cz[off] = acc[m][n][r];
          else          C[off] += acc[m][n][r];
        }
      }
    }
  }
}

// Head fallback when ws can't hold bf16 w_out.
__global__ __launch_bounds__(256) void k_gemm_hf(const u16* __restrict__ A,
                                                 const float* __restrict__ B,
                                                 float* __restrict__ C,
                                                 int N, int K, int Mstore)
{
  __shared__ u16 As[4096];
  __shared__ u16 Bs[4096];
  const int tid = threadIdx.x;
  const int bm = blockIdx.y * 128, bn = blockIdx.x * 128;
  const int w = tid >> 6, lane = tid & 63;
  const int wm = (w >> 1) * 64, wn = (w & 1) * 64;
  const int lr = lane & 15, kh = lane >> 4;
  const int r0 = tid >> 2, kc0 = (tid & 3) * 8;
  const u16* ga = A + (size_t)(bm + r0) * K + kc0;
  u16* la = &As[tid * 8];
  const size_t rstep = (size_t)64 * K;

  f32x4 acc[4][4] = {};
  for (int kk = 0; kk < K; kk += 32) {
    GLOAD16(ga, la); GLOAD16(ga + rstep, la + 2048);
    ga += 32;
#pragma unroll
    for (int p = 0; p < 4; ++p) {
      int e = tid + p * 256;
      int row = e >> 3, kc = (e & 7) * 4;
      float4 v = *(const float4*)(B + (size_t)(bn + row) * K + kk + kc);
      us4 pk; pk[0] = f2bf(v.x); pk[1] = f2bf(v.y); pk[2] = f2bf(v.z); pk[3] = f2bf(v.w);
      *(us4*)&Bs[row * 32 + kc] = pk;
    }
    __syncthreads();
    bf16x8 af[4], bfr[4];
#pragma unroll
    for (int m = 0; m < 4; ++m)
      af[m] = *(const bf16x8*)&As[(wm + m * 16 + lr) * 32 + kh * 8];
#pragma unroll
    for (int n = 0; n < 4; ++n)
      bfr[n] = *(const bf16x8*)&Bs[(wn + n * 16 + lr) * 32 + kh * 8];
#pragma unroll
    for (int m = 0; m < 4; ++m)
#pragma unroll
      for (int n = 0; n < 4; ++n)
        acc[m][n] = __builtin_amdgcn_mfma_f32_16x16x32_bf16(af[m], bfr[n], acc[m][n], 0, 0, 0);
    __syncthreads();
  }
#pragma unroll
  for (int m = 0; m < 4; ++m) {
    int gr0 = bm + wm + m * 16 + kh * 4;
#pragma unroll
    for (int n = 0; n < 4; ++n) {
      int gc = bn + wn + n * 16 + lr;
#pragma unroll
      for (int r = 0; r < 4; ++r) {
        int gr = gr0 + r;
        if (gr < Mstore) C[(size_t)gr * N + gc] = acc[m][n][r];
      }
    }
  }
}

// ---------------- weight transpose-convert: W[K,N] f32 -> Wt[N,K] bf16 ----------------
__global__ __launch_bounds__(256) void k_wt(const float* __restrict__ W, u16* __restrict__ Wt,
                                            int K, int N) {
  __shared__ u16 t[64][80];
  int n0 = blockIdx.x * 64, k0 = blockIdx.y * 64;
#pragma unroll
  for (int p = 0; p < 4; ++p) {
    int id = threadIdx.x + p * 256;
    int row = id >> 4, c4 = (id & 15) * 4;
    float4 v = *(const float4*)(W + (size_t)(k0 + row) * N + n0 + c4);
    t[c4 + 0][row] = f2bf(v.x);
    t[c4 + 1][row] = f2bf(v.y);
    t[c4 + 2][row] = f2bf(v.z);
    t[c4 + 3][row] = f2bf(v.w);
  }
  __syncthreads();
#pragma unroll
  for (int p = 0; p < 2; ++p) {
    int id = threadIdx.x + p * 256;
    int row = id >> 3, c8 = (id & 7) * 8;
    *(us8*)(Wt + (size_t)(n0 + row) * K + k0 + c8) = *(const us8*)&t[row][c8];
  }
}

// ---------------- flat f32 -> bf16 convert ----------------
__global__ void k_cvt(const float* __restrict__ x, u16* __restrict__ y, int n4) {
  for (int i = blockIdx.x * 256 + threadIdx.x; i < n4; i += gridDim.x * 256) {
    float4 v = ((const float4*)x)[i];
    us4 p; p[0] = f2bf(v.x); p[1] = f2bf(v.y); p[2] = f2bf(v.z); p[3] = f2bf(v.w);
    ((us4*)y)[i] = p;
  }
}

__global__ void k_reduce16(const float* __restrict__ p, float* __restrict__ o) {
  int i = blockIdx.x * 256 + threadIdx.x;
  if (i >= 128 * 1024) return;
  float s = 0.f;
#pragma unroll
  for (int z = 0; z < 16; ++z) s += p[z * 131072 + i];
  o[i] = s;
}

__global__ void k_rope_table(float* __restrict__ cosT, float* __restrict__ sinT) {
  int i = blockIdx.x * blockDim.x + threadIdx.x;
  if (i >= 18 * 64) return;
  int p = i >> 6, d = i & 63;
  float theta = powf(10000.f, -(float)(d & 31) / 32.f);
  float ang = (float)p * theta;
  cosT[i] = cosf(ang);
  sinT[i] = sinf(ang);
}

__global__ void k_fine_embed(const int* __restrict__ ids, const int* __restrict__ cspp,
                             const float* __restrict__ f_wte, const float* __restrict__ f_pos,
                             const float* __restrict__ f_adapt, float* __restrict__ xF) {
  int csp = fix_csp(cspp);
  for (int idx = blockIdx.x * 256 + threadIdx.x; idx < T_FINE * 1024; idx += gridDim.x * 256) {
    int r = idx >> 10, d = idx & 1023;
    int c = r / 18, j = r - c * 18;
    float v;
    if (j == 0)      v = f_adapt[csp * 1024 + d];
    else if (j == 1) v = f_pos[c * 1024 + d];
    else             v = f_wte[(size_t)ids[c * 16 + j - 2] * 1024 + d];
    xF[idx] = v;
  }
}

// ---------------- rmsnorm -> bf16 out ----------------
__global__ __launch_bounds__(256) void k_rmsnorm_bf(const float* __restrict__ x,
                                                    const float* __restrict__ w,
                                                    u16* __restrict__ y) {
  int t = blockIdx.x;
  const float4 v = *(const float4*)(x + (size_t)t * 1024 + threadIdx.x * 4);
  float ss = v.x * v.x + v.y * v.y + v.z * v.z + v.w * v.w;
#pragma unroll
  for (int off = 32; off; off >>= 1) ss += __shfl_xor(ss, off);
  __shared__ float ps[4];
  if ((threadIdx.x & 63) == 0) ps[threadIdx.x >> 6] = ss;
  __syncthreads();
  float inv = rsqrtf((ps[0] + ps[1] + ps[2] + ps[3]) * (1.f / 1024.f) + 1e-5f);
  const float4 wv = *(const float4*)(w + threadIdx.x * 4);
  us4 o;
  o[0] = f2bf(v.x * inv * wv.x); o[1] = f2bf(v.y * inv * wv.y);
  o[2] = f2bf(v.z * inv * wv.z); o[3] = f2bf(v.w * inv * wv.w);
  *(us4*)(y + (size_t)t * 1024 + threadIdx.x * 4) = o;
}

// rmsnorm fine-final, drop rows 0,1 per chunk -> packed bf16 [128][16384]
__global__ __launch_bounds__(256) void k_rmsnorm_pack_bf(const float* __restrict__ x,
                                                         const float* __restrict__ w,
                                                         u16* __restrict__ y) {
  int b = blockIdx.x;            // c*16 + r
  int c = b >> 4, r = b & 15;
  const float* xr = x + (size_t)(c * 18 + 2 + r) * 1024;
  const float4 v = *(const float4*)(xr + threadIdx.x * 4);
  float ss = v.x * v.x + v.y * v.y + v.z * v.z + v.w * v.w;
#pragma unroll
  for (int off = 32; off; off >>= 1) ss += __shfl_xor(ss, off);
  __shared__ float ps[4];
  if ((threadIdx.x & 63) == 0) ps[threadIdx.x >> 6] = ss;
  __syncthreads();
  float inv = rsqrtf((ps[0] + ps[1] + ps[2] + ps[3]) * (1.f / 1024.f) + 1e-5f);
  const float4 wv = *(const float4*)(w + threadIdx.x * 4);
  us4 o;
  o[0] = f2bf(v.x * inv * wv.x); o[1] = f2bf(v.y * inv * wv.y);
  o[2] = f2bf(v.z * inv * wv.z); o[3] = f2bf(v.w * inv * wv.w);
  *(us4*)(y + (size_t)b * 1024 + threadIdx.x * 4) = o;
}

// ---------------- rope in-place on q,k of qkv[T][3072] f32; pos = t % 18 ----------------
__global__ __launch_bounds__(256) void k_rope(float* __restrict__ qkv,
                                              const float* __restrict__ cosT,
                                              const float* __restrict__ sinT) {
  int t = blockIdx.x;
  int p = t % 18;
  float* row = qkv + (size_t)t * 3072;
#pragma unroll
  for (int i = 0; i < 4; ++i) {
    int it = threadIdx.x + i * 256;
    int s = it >> 9, rem = it & 511, h = rem >> 5, d = rem & 31;
    float* px = row + s * 1024 + h * 64 + d;
    float x1 = px[0], x2 = px[32];
    float cv = cosT[p * 64 + d], sv = sinT[p * 64 + d];
    px[0]  = x1 * cv - x2 * sv;
    px[32] = x2 * cv + x1 * sv;
  }
}

// ---------------- fine attention v2: 4 waves/block, wave = head, LDS-staged ----------------
__global__ __launch_bounds__(256) void k_attn_fine2(const float* __restrict__ qkv,
                                                    u16* __restrict__ out) {
  __shared__ float q[4][18][68], k[4][18][68], v[4][18][68], s[4][18][20];
  int c = blockIdx.x;
  int w = threadIdx.x >> 6, lane = threadIdx.x & 63;
  int h = blockIdx.y * 4 + w;
  const float* base = qkv + (size_t)c * 18 * 3072 + h * 64;
#pragma unroll 3
  for (int r = 0; r < 18; ++r) {
    q[w][r][lane] = base[(size_t)r * 3072 + lane];
    k[w][r][lane] = base[(size_t)r * 3072 + 1024 + lane];
    v[w][r][lane] = base[(size_t)r * 3072 + 2048 + lane];
  }
  __syncthreads();
  // scores: 324 (qi,ki) pairs across 64 lanes
#pragma unroll
  for (int it = 0; it < 6; ++it) {
    int idx = lane + it * 64;
    if (idx < 324) {
      int qi = (idx * 3641) >> 16;        // idx/18 for idx<324
      int ki = idx - qi * 18;
      const float* qr = q[w][qi];
      const float* kr = k[w][ki];
      float a = 0.f;
#pragma unroll
      for (int d = 0; d < 64; d += 4) {
        float4 x = *(const float4*)&qr[d];
        float4 y = *(const float4*)&kr[d];
        a += x.x * y.x + x.y * y.y + x.z * y.z + x.w * y.w;
      }
      s[w][qi][ki] = a * 0.125f;
    }
  }
  __syncthreads();
  if (lane < 18) {
    float mx = -1e30f;
#pragma unroll
    for (int j = 0; j < 18; ++j) mx = fmaxf(mx, s[w][lane][j]);
    float sum = 0.f;
#pragma unroll
    for (int j = 0; j < 18; ++j) { float e = expf(s[w][lane][j] - mx); s[w][lane][j] = e; sum += e; }
    float inv = 1.f / sum;
#pragma unroll
    for (int j = 0; j < 18; ++j) s[w][lane][j] *= inv;
  }
  __syncthreads();
  float vcol[18];
#pragma unroll
  for (int ki = 0; ki < 18; ++ki) vcol[ki] = v[w][ki][lane];
#pragma unroll 2
  for (int qi = 0; qi < 18; ++qi) {
    float o = 0.f;
#pragma unroll
    for (int ki = 0; ki < 18; ++ki) o += s[w][qi][ki] * vcol[ki];
    out[(size_t)(c * 18 + qi) * 1024 + h * 64 + lane] = f2bf(o);
  }
}

// ---------------- decoder attention v2: 4 waves/block, wave = head ----------------
__global__ __launch_bounds__(256) void k_attn_dec2(const float* __restrict__ qkv,
                                                   u16* __restrict__ out) {
  __shared__ float sc_s[4][160];
  int t = blockIdx.x;
  int w = threadIdx.x >> 6, lane = threadIdx.x & 63;
  int h = blockIdx.y * 4 + w;
  float* sc = sc_s[w];
  int bq = t / 18;
  int nstart = bq + 1;            // kv = 18*m, m in [0,bq]
  int nown = t - 18 * bq;         // kv = 18*bq+1 .. t
  int nk = nstart + nown;         // <= 145
  int g = lane >> 2, j = lane & 3;
  const float* qb = qkv + (size_t)t * 3072 + h * 64 + j * 16;
  float4 q0 = *(const float4*)(qb);
  float4 q1 = *(const float4*)(qb + 4);
  float4 q2 = *(const float4*)(qb + 8);
  float4 q3 = *(const float4*)(qb + 12);
  for (int i0 = 0; i0 < nk; i0 += 16) {
    int i = i0 + g;
    float p = 0.f;
    if (i < nk) {
      int kv = (i < nstart) ? 18 * i : 18 * bq + (i - nstart) + 1;
      const float* kp = qkv + (size_t)kv * 3072 + 1024 + h * 64 + j * 16;
      float4 k0 = *(const float4*)(kp);
      float4 k1 = *(const float4*)(kp + 4);
      float4 k2 = *(const float4*)(kp + 8);
      float4 k3 = *(const float4*)(kp + 12);
      p = q0.x * k0.x + q0.y * k0.y + q0.z * k0.z + q0.w * k0.w
        + q1.x * k1.x + q1.y * k1.y + q1.z * k1.z + q1.w * k1.w
        + q2.x * k2.x + q2.y * k2.y + q2.z * k2.z + q2.w * k2.w
        + q3.x * k3.x + q3.y * k3.y + q3.z * k3.z + q3.w * k3.w;
    }
    p += __shfl_xor(p, 1);
    p += __shfl_xor(p, 2);
    if (i < nk && j == 0) sc[i] = p * 0.125f;
  }
  __syncthreads();
  float mx = -1e30f;
  for (int i = lane; i < nk; i += 64) mx = fmaxf(mx, sc[i]);
#pragma unroll
  for (int off = 32; off; off >>= 1) mx = fmaxf(mx, __shfl_xor(mx, off));
  float sum = 0.f;
  for (int i = lane; i < nk; i += 64) { float e = expf(sc[i] - mx); sc[i] = e; sum += e; }
#pragma unroll
  for (int off = 32; off; off >>= 1) sum += __shfl_xor(sum, off);
  float inv = 1.f / sum;
  __syncthreads();
  const float* vb = qkv + 2048 + h * 64 + lane;
  float o0 = 0.f, o1 = 0.f, o2 = 0.f, o3 = 0.f;
  int i = 0;
  for (; i + 4 <= nk; i += 4) {
    int ia = i, ib = i + 1, ic = i + 2, id = i + 3;
    int kva = (ia < nstart) ? 18 * ia : 18 * bq + (ia - nstart) + 1;
    int kvb = (ib < nstart) ? 18 * ib : 18 * bq + (ib - nstart) + 1;
    int kvc = (ic < nstart) ? 18 * ic : 18 * bq + (ic - nstart) + 1;
    int kvd = (id < nstart) ? 18 * id : 18 * bq + (id - nstart) + 1;
    o0 += sc[ia] * vb[(size_t)kva * 3072];
    o1 += sc[ib] * vb[(size_t)kvb * 3072];
    o2 += sc[ic] * vb[(size_t)kvc * 3072];
    o3 += sc[id] * vb[(size_t)kvd * 3072];
  }
  for (; i < nk; ++i) {
    int kv = (i < nstart) ? 18 * i : 18 * bq + (i - nstart) + 1;
    o0 += sc[i] * vb[(size_t)kv * 3072];
  }
  float o = (o0 + o1) + (o2 + o3);
  out[(size_t)t * 1024 + h * 64 + lane] = f2bf(o * inv);
}

// ---------------- silu(g)*u on fused [rows][8192] (g|u) -> bf16 [rows][4096] ----------------
__global__ void k_silumul_bf2(const float* __restrict__ gu, u16* __restrict__ y, int rows) {
  int total = rows * 1024;
  for (int i = blockIdx.x * 256 + threadIdx.x; i < total; i += gridDim.x * 256) {
    int r = i >> 10, c4 = i & 1023;
    const float4 a = *(const float4*)(gu + (size_t)r * 8192 + c4 * 4);
    const float4 b = *(const float4*)(gu + (size_t)r * 8192 + 4096 + c4 * 4);
    us4 o;
    o[0] = f2bf(a.x / (1.f + expf(-a.x)) * b.x);
    o[1] = f2bf(a.y / (1.f + expf(-a.y)) * b.y);
    o[2] = f2bf(a.z / (1.f + expf(-a.z)) * b.z);
    o[3] = f2bf(a.w / (1.f + expf(-a.w)) * b.w);
    *(us4*)(y + (size_t)r * 4096 + c4 * 4) = o;
  }
}

// ---------------- decoder input assembly (zeroes pad rows 2306..2431) ----------------
__global__ void k_assemble(const int* __restrict__ ids, const int* __restrict__ cspp,
                           const float* __restrict__ fx, const float* __restrict__ dummy_fx,
                           const float* __restrict__ sep, const float* __restrict__ wte,
                           float* __restrict__ xD) {
  int csp = fix_csp(cspp);
  for (int idx = blockIdx.x * 256 + threadIdx.x; idx < MPAD * 1024; idx += gridDim.x * 256) {
    int t = idx >> 10, d = idx & 1023;
    float v;
    if (t >= L_DEC)     v = 0.f;
    else if (t == 2305) v = sep[d];
    else if (t == 2304) v = fx[127 * 1024 + d];
    else {
      int k = t / 18, r = t - k * 18;
      if (r == 0)      v = (k == 0) ? dummy_fx[csp * 1024 + d] : fx[(k - 1) * 1024 + d];
      else if (r == 1) v = sep[d];
      else             v = wte[(size_t)ids[k * 16 + r - 2] * 1024 + d];
    }
    xD[idx] = v;
  }
}

extern "C" void kernel_launch(void* const* d_in, const int* in_sizes, int n_in,
                              void* d_out, int out_size, void* d_ws, size_t ws_size,
                              hipStream_t stream) {
  const int*   input_ids = (const int*)d_in[0];
  const int*   cspp      = (const int*)d_in[1];
  const float* f_wte     = (const float*)d_in[2];
  const float* f_pos     = (const float*)d_in[3];
  const float* f_adapt   = (const float*)d_in[4];
  const float* f_ln1     = (const float*)d_in[5];
  const float* f_ln2     = (const float*)d_in[6];
  const float* f_wqkv    = (const float*)d_in[7];
  const float* f_wo      = (const float*)d_in[8];
  const float* f_wg      = (const float*)d_in[9];
  const float* f_wu      = (const float*)d_in[10];
  const float* f_wd      = (const float*)d_in[11];
  const float* f_norm    = (const float*)d_in[12];
  const float* f_proj    = (const float*)d_in[13];
  const float* dummy_fx  = (const float*)d_in[14];
  const float* wte       = (const float*)d_in[15];
  const float* sep       = (const float*)d_in[16];
  const float* d_ln1     = (const float*)d_in[17];
  const float* d_ln2     = (const float*)d_in[18];
  const float* d_wqkv    = (const float*)d_in[19];
  const float* d_wo      = (const float*)d_in[20];
  const float* d_wg      = (const float*)d_in[21];
  const float* d_wu      = (const float*)d_in[22];
  const float* d_wd      = (const float*)d_in[23];
  const float* d_norm    = (const float*)d_in[24];
  const float* w_out     = (const float*)d_in[25];

  // ---- d_ws: rope tables + bufH (bf16) + (if room) bf16 w_out ----
  float* cosT = (float*)d_ws;
  float* sinT = cosT + 1152;
  u16*   bufH = (u16*)(sinT + 1152);                 // [MPAD][1024] bf16
  u16*   w_outb = bufH + (size_t)MPAD * 1024;        // [32000][1024] bf16 (optional)
  const size_t WS_NEED = 2 * 1152 * 4 + (size_t)MPAD * 1024 * 2 + (size_t)32000 * 1024 * 2;
  const bool big_ws = ws_size >= WS_NEED;

  // ---- d_out scratch (head GEMM reads only ws buffers, so it may overwrite all of this) ----
  float* o       = (float*)d_out;
  float* xF      = o;                                   // [2304][1024] f32
  float* xD      = xF + (size_t)T_FINE * 1024;          // [MPAD][1024] f32
  float* fx      = xD + (size_t)MPAD * 1024;            // [128][1024] f32
  float* bufQKV  = fx + 128 * 1024;                     // [MPAD][3072] f32 (also split-K partials)
  float* bufG    = bufQKV + (size_t)MPAD * 3072;        // [MPAD][8192] f32 fused g|u
  u16*   bufA    = (u16*)(bufG + (size_t)MPAD * 8192);  // [MPAD][1024] bf16
  u16*   bufGb   = bufA + (size_t)MPAD * 1024;          // [MPAD][4096] bf16
  u16*   packedb = bufGb + (size_t)MPAD * 4096;         // [128][16384] bf16
  u16*   Wt      = packedb + (size_t)128 * 16384;       // [8192][1024] bf16 staging
  u16*   projb   = Wt + (size_t)8192 * 1024;            // [1024][16384] bf16

#define GEMM_BT(EPI, Ap, Bp, Cp, Mpad, N, K, Mstore, S) \
  k_gemm_bt<EPI><<<dim3((N) / 128, (Mpad) / 128, (S)), 256, 0, stream>>>((Ap), (Bp), (Cp), (N), (K), (Mstore), (K) / (S))

  k_rope_table<<<5, 256, 0, stream>>>(cosT, sinT);
  k_fine_embed<<<2048, 256, 0, stream>>>(input_ids, cspp, f_wte, f_pos, f_adapt, xF);

  // ---- fine (compressor) layers: M = 2304 exact ----
  for (int i = 0; i < 2; ++i) {
    k_rmsnorm_bf<<<T_FINE, 256, 0, stream>>>(xF, f_ln1 + i * 1024, bufH);
    k_wt<<<dim3(48, 16), 256, 0, stream>>>(f_wqkv + (size_t)i * 1024 * 3072, Wt, 1024, 3072);
    GEMM_BT(0, bufH, Wt, bufQKV, T_FINE, 3072, 1024, T_FINE, 1);
    k_rope<<<T_FINE, 256, 0, stream>>>(bufQKV, cosT, sinT);
    k_attn_fine2<<<dim3(128, 4), 256, 0, stream>>>(bufQKV, bufA);
    k_wt<<<dim3(16, 16), 256, 0, stream>>>(f_wo + (size_t)i * 1024 * 1024, Wt, 1024, 1024);
    GEMM_BT(1, bufA, Wt, xF, T_FINE, 1024, 1024, T_FINE, 1);
    k_rmsnorm_bf<<<T_FINE, 256, 0, stream>>>(xF, f_ln2 + i * 1024, bufH);
    k_wt<<<dim3(64, 16), 256, 0, stream>>>(f_wg + (size_t)i * 1024 * 4096, Wt, 1024, 4096);
    k_wt<<<dim3(64, 16), 256, 0, stream>>>(f_wu + (size_t)i * 1024 * 4096, Wt + (size_t)4096 * 1024, 1024, 4096);
    GEMM_BT(0, bufH, Wt, bufG, T_FINE, 8192, 1024, T_FINE, 1);
    k_silumul_bf2<<<2048, 256, 0, stream>>>(bufG, bufGb, T_FINE);
    k_wt<<<dim3(16, 64), 256, 0, stream>>>(f_wd + (size_t)i * 4096 * 1024, Wt, 4096, 1024);
    GEMM_BT(1, bufGb, Wt, xF, T_FINE, 1024, 4096, T_FINE, 1);
  }

  // ---- fx = packed @ f_proj^T : f_proj is [1024][16384] = [N][K] already; split-K 16 ----
  k_rmsnorm_pack_bf<<<2048, 256, 0, stream>>>(xF, f_norm, packedb);
  k_cvt<<<2048, 256, 0, stream>>>(f_proj, projb, 1024 * 16384 / 4);
  GEMM_BT(0, packedb, projb, bufQKV, 128, 1024, 16384, 128, 16);
  k_reduce16<<<512, 256, 0, stream>>>(bufQKV, fx);

  // ---- decoder: M padded to 2432 ----
  k_assemble<<<2048, 256, 0, stream>>>(input_ids, cspp, fx, dummy_fx, sep, wte, xD);
  for (int i = 0; i < 2; ++i) {
    k_rmsnorm_bf<<<MPAD, 256, 0, stream>>>(xD, d_ln1 + i * 1024, bufH);
    k_wt<<<dim3(48, 16), 256, 0, stream>>>(d_wqkv + (size_t)i * 1024 * 3072, Wt, 1024, 3072);
    GEMM_BT(0, bufH, Wt, bufQKV, MPAD, 3072, 1024, MPAD, 1);
    k_rope<<<L_DEC, 256, 0, stream>>>(bufQKV, cosT, sinT);
    k_attn_dec2<<<dim3(L_DEC, 4), 256, 0, stream>>>(bufQKV, bufA);
    k_wt<<<dim3(16, 16), 256, 0, stream>>>(d_wo + (size_t)i * 1024 * 1024, Wt, 1024, 1024);
    GEMM_BT(1, bufA, Wt, xD, MPAD, 1024, 1024, MPAD, 1);
    k_rmsnorm_bf<<<MPAD, 256, 0, stream>>>(xD, d_ln2 + i * 1024, bufH);
    k_wt<<<dim3(64, 16), 256, 0, stream>>>(d_wg + (size_t)i * 1024 * 4096, Wt, 1024, 4096);
    k_wt<<<dim3(64, 16), 256, 0, stream>>>(d_wu + (size_t)i * 1024 * 4096, Wt + (size_t)4096 * 1024, 1024, 4096);
    GEMM_BT(0, bufH, Wt, bufG, MPAD, 8192, 1024, MPAD, 1);
    k_silumul_bf2<<<2048, 256, 0, stream>>>(bufG, bufGb, MPAD);
    k_wt<<<dim3(16, 64), 256, 0, stream>>>(d_wd + (size_t)i * 4096 * 1024, Wt, 4096, 1024);
    GEMM_BT(1, bufGb, Wt, xD, MPAD, 1024, 4096, MPAD, 1);
  }

  // ---- head: out = rmsnorm(xD) @ w_out^T ; w_out is [32000][1024] = [N][K] already ----
  k_rmsnorm_bf<<<MPAD, 256, 0, stream>>>(xD, d_norm, bufH);
  if (big_ws) {
    k_cvt<<<2048, 256, 0, stream>>>(w_out, w_outb, 32000 * 1024 / 4);
    GEMM_BT(0, bufH, w_outb, o, MPAD, 32000, 1024, L_DEC, 1);
  } else {
    k_gemm_hf<<<dim3(250, 19), 256, 0, stream>>>(bufH, w_out, o, 32000, 1024, L_DEC);
  }
#undef GEMM_BT
}